// Round 8
// baseline (150.931 us; speedup 1.0000x reference)
//
#include <hip/hip_runtime.h>
#include <math.h>

// ---------------------------------------------------------------------------
// TMCAM, R23 = R22 RESUBMIT (round 7 was an infra failure: "MI355X container
// failed twice" — kernel never ran; no verdict). Content unchanged:
// R22 = R21 agg_tile (champion, 148.7us) + small-kernel traffic fixes:
//  (1) final_kernel: 4 o's per block (blockIdx.y 128->32). a1 L2 re-read
//      traffic 113MB -> 28MB (a1 is 3.5MB, was read 128x). The 4 o's are one
//      2x2 pixel-shuffle quad -> two coalesced float2 stores. FP order per o
//      preserved exactly (same 4-partial-chain structure).
//  (2) up2_kernel: one thread = even/odd x-pair; 6 loads per pair (was 8),
//      float2 store. Interp expression keeps original ordering bit-for-bit.
// R21 post-mortem: convoy bundle WIN (151.8->148.7). Session law: latency/
// convoy fixes pay (R17/R20/R21); work-shuffles neutral (R18); occupancy
// bets regress (R16/R19).
// Ledger of banned moves (all measured): grid.sync (R10, ~80us each);
// fused-up2-in-staging (R6); P4 full p-loop unroll (R2/R7 spill); small tiles
// (R9); P4 unit remap (R13/R14); OSPLIT (R16, +11us); 5-wave blocks w/ tight
// launch_bounds (R19, VGPR cap 64 -> scratch spill; spill signature =
// WRITE_SIZE explosion at LOW reported VGPR).
// ---------------------------------------------------------------------------

template<int D, int TS, int H, int W, bool HA>
__global__ __launch_bounds__(256, 3)
void agg_tile(const float* __restrict__ feats,   // (32, 3, H, W)
              const float* __restrict__ add,     // (3, 32, H, W) or null
              const float* __restrict__ agg_w,   // (4)
              const float* __restrict__ agg_b,   // (1)
              const float* __restrict__ wp_w,    // (288, 64) row-major
              const float* __restrict__ wp_b,    // (288)
              float* __restrict__ out)           // (3, 32, H, W)
{
    constexpr int PD = D / 2;
    constexpr int M  = PD + 1;            // stage margin (disp + 3x3 unfold)
    constexpr int R  = TS + 2 * M;        // sA region edge
    constexpr int S  = TS + 2;            // sC region edge
    constexpr int S2 = S * S;
    constexpr int D2 = D * D;
    constexpr int NP = TS * TS;
    constexpr int NX = S2 * D2;
    constexpr int NSIM = NP * D2;
    constexpr int CS = 36;                // padded per-pos float stride
    constexpr int UST = 292;              // U row stride (292 % 32 = 4: no
                                          // 9-way P5 bank conflict like 288)
    constexpr int USZ = (NP * UST > NX + NSIM) ? NP * UST : NX + NSIM;
    constexpr int TPW = W / TS;
    constexpr int NPA = R * R;
    constexpr int GA  = 256 / NPA;        // channel groups for sA staging
    constexpr int NPS = S * S;
    constexpr int GS  = 256 / NPS;
    constexpr int NITA = (32 + GA - 1) / GA;  // channel iters per sA thread
    constexpr int NITS = (32 + GS - 1) / GS;  // channel iters per sC thread

    __shared__ float sA[NPA * CS];        // feat_tm1 (+add), [pos][c]
    __shared__ float sC[NPS * CS];        // feat_t center (+add), [pos][c]
    __shared__ float t2[NPA];             // sum_c sA^2 per pos
    __shared__ float s2[NPS];             // sum_c sC^2 per pos
    __shared__ float U[USZ];              // X | sSim, then final product
    __shared__ int   sIdx[NP * 4];        // top-4 sA offsets (pre-scaled) or -1

    float* Xarr = U;                      // NX entries, [u*D2+dd]
    float* sSim = U + NX;                 // NSIM entries

    const int tid  = threadIdx.x;
    const int tile = blockIdx.x;
    const int t    = blockIdx.y;
    const int y0 = (tile / TPW) * TS;
    const int x0 = (tile % TPW) * TS;

    const float* addT = HA ? (add + (size_t)t * 32 * H * W) : nullptr;

    // ---- P0: stage sA (frame t + add) / sC (frame 1 + add). Chunked
    //      reg-buffered: 8 channel loads in flight, then 8 LDS writes
    //      (kills the unroll-1 load->write serial latency chain). ----
    if (tid < NPA * GA) {
        const int pos = tid % NPA;
        const int cb  = tid / NPA;
        const int ry = pos / R, rx = pos % R;
        const int yy = y0 - M + ry, xx = x0 - M + rx;
        float* dst = sA + pos * CS;
        if (yy >= 0 && yy < H && xx >= 0 && xx < W) {
            const float* sF = feats + (((size_t)cb * 3 + t) * H + yy) * W + xx;
            const float* sD = HA ? (addT + ((size_t)cb * H + yy) * W + xx) : nullptr;
            #pragma unroll 1
            for (int kb = 0; kb < NITA; kb += 8) {
                float v[8];
                #pragma unroll
                for (int u = 0; u < 8; ++u) {
                    const int k = kb + u;
                    const int c = cb + k * GA;
                    if (k < NITA && c < 32) {
                        float x = sF[(size_t)k * GA * 3 * H * W];
                        if (HA) x += sD[(size_t)k * GA * H * W];
                        v[u] = x;
                    }
                }
                #pragma unroll
                for (int u = 0; u < 8; ++u) {
                    const int k = kb + u;
                    const int c = cb + k * GA;
                    if (k < NITA && c < 32) dst[c] = v[u];
                }
            }
        } else {
            #pragma unroll 1
            for (int c = cb; c < 32; c += GA) dst[c] = 0.f;
        }
    }
    if (tid < NPS * GS) {
        const int pos = tid % NPS;
        const int cb  = tid / NPS;
        const int ry = pos / S, rx = pos % S;
        const int yy = y0 - 1 + ry, xx = x0 - 1 + rx;
        float* dst = sC + pos * CS;
        if (yy >= 0 && yy < H && xx >= 0 && xx < W) {
            const float* sF = feats + (((size_t)cb * 3 + 1) * H + yy) * W + xx;
            const float* sD = HA ? (addT + ((size_t)cb * H + yy) * W + xx) : nullptr;
            #pragma unroll 1
            for (int kb = 0; kb < NITS; kb += 8) {
                float v[8];
                #pragma unroll
                for (int u = 0; u < 8; ++u) {
                    const int k = kb + u;
                    const int c = cb + k * GS;
                    if (k < NITS && c < 32) {
                        float x = sF[(size_t)k * GS * 3 * H * W];
                        if (HA) x += sD[(size_t)k * GS * H * W];
                        v[u] = x;
                    }
                }
                #pragma unroll
                for (int u = 0; u < 8; ++u) {
                    const int k = kb + u;
                    const int c = cb + k * GS;
                    if (k < NITS && c < 32) dst[c] = v[u];
                }
            }
        } else {
            #pragma unroll 1
            for (int c = cb; c < 32; c += GS) dst[c] = 0.f;
        }
    }
    __syncthreads();

    // ---- P1: X (thread = (u,di), sC row cached in regs, D indep dj dots
    //      -> cross-dj ILP already), t2, s2 ----
    if (tid < S2 * D) {
        const int u  = tid / D;
        const int di = tid - u * D;
        const int uy = u / S, ux = u - uy * S;
        float4 cv[8];
        const float4* c4 = (const float4*)(sC + u * CS);
        #pragma unroll
        for (int i = 0; i < 8; ++i) cv[i] = c4[i];
        const float* arow = sA + ((uy + di) * R + ux) * CS;
        float* xrow = Xarr + u * D2 + di * D;
        #pragma unroll
        for (int dj = 0; dj < D; ++dj) {
            const float4* a4 = (const float4*)(arow + dj * CS);
            float s = 0.f;
            #pragma unroll
            for (int i = 0; i < 8; ++i) {
                float4 av = a4[i];
                s += cv[i].x * av.x + cv[i].y * av.y + cv[i].z * av.z + cv[i].w * av.w;
            }
            xrow[dj] = s;
        }
    }
    for (int e = tid; e < NPA; e += 256) {
        const float4* a4 = (const float4*)(sA + e * CS);
        float4 s4 = make_float4(0.f, 0.f, 0.f, 0.f);
        #pragma unroll
        for (int cc = 0; cc < 8; ++cc) {
            float4 v = a4[cc];
            s4.x += v.x * v.x; s4.y += v.y * v.y;
            s4.z += v.z * v.z; s4.w += v.w * v.w;
        }
        t2[e] = (s4.x + s4.y) + (s4.z + s4.w);
    }
    for (int e = tid; e < NPS; e += 256) {
        const float4* c4 = (const float4*)(sC + e * CS);
        float4 s4 = make_float4(0.f, 0.f, 0.f, 0.f);
        #pragma unroll
        for (int cc = 0; cc < 8; ++cc) {
            float4 v = c4[cc];
            s4.x += v.x * v.x; s4.y += v.y * v.y;
            s4.z += v.z * v.z; s4.w += v.w * v.w;
        }
        s2[e] = (s4.x + s4.y) + (s4.z + s4.w);
    }
    __syncthreads();

    // ---- P2: sims (mask out-of-image displaced centers to exactly 0) ----
    for (int e = tid; e < NSIM; e += 256) {
        int p = e / D2, dd = e - p * D2;
        int py = p / TS, px = p - py * TS;
        int di = dd / D, dj = dd - di * D;
        int Yc = y0 + py + di - PD, Xc = x0 + px + dj - PD;
        float sim = 0.f;
        if (Yc >= 0 && Yc < H && Xc >= 0 && Xc < W) {
            float dot = 0.f, n2 = 0.f, nf = 0.f;
            #pragma unroll
            for (int qi = 0; qi < 3; ++qi)
            #pragma unroll
            for (int qj = 0; qj < 3; ++qj) {
                dot += Xarr[((py + qi) * S + (px + qj)) * D2 + dd];
                n2  += t2[(py + qi + di) * R + (px + qj + dj)];
                nf  += s2[(py + qi) * S + (px + qj)];
            }
            sim = dot / fmaxf(sqrtf(nf), 1e-12f) / fmaxf(sqrtf(n2), 1e-12f);
        }
        sSim[e] = sim;
    }
    __syncthreads();

    // ---- P3: per-pixel top-4 (strict-insert == stable ties, lax.top_k);
    //      store pre-scaled sA offsets ----
    if (tid < NP) {
        float v0 = -3.0e38f, v1 = -3.0e38f, v2 = -3.0e38f, v3 = -3.0e38f;
        int   i0 = 0, i1 = 0, i2 = 0, i3 = 0;
        const float* row = sSim + tid * D2;
        for (int dd = 0; dd < D2; ++dd) {
            float v = row[dd];
            if (v > v0)      { v3=v2;i3=i2; v2=v1;i2=i1; v1=v0;i1=i0; v0=v;i0=dd; }
            else if (v > v1) { v3=v2;i3=i2; v2=v1;i2=i1; v1=v;i1=dd; }
            else if (v > v2) { v3=v2;i3=i2; v2=v;i2=dd; }
            else if (v > v3) { v3=v;i3=dd; }
        }
        int py = tid / TS, px = tid - (tid / TS) * TS;
        int ids[4] = {i0, i1, i2, i3};
        #pragma unroll
        for (int k = 0; k < 4; ++k) {
            int dd = ids[k];
            int di = dd / D, dj = dd - di * D;
            int Yc = y0 + py + di - PD, Xc = x0 + px + dj - PD;
            sIdx[tid * 4 + k] = (Yc >= 0 && Yc < H && Xc >= 0 && Xc < W)
                              ? (di * R + dj) * CS : -1;
        }
    }
    __syncthreads();

    // ---- P4 (fused): both wm halves + aggd gather + multiply in ONE pass.
    //      Main: each thread does exactly one o = tid. Tail o in [256,288):
    //      lanes 0-31 of waves 1/2/3, each covering 1/3 of the p-range
    //      (critical path ~960 insts vs the old wave-0 double sweep ~1440).
    //      setprio(1) favors P4 waves over other blocks' staging (T5). ----
    const float4* wp4 = (const float4*)wp_w;
    const float aw0 = agg_w[0], aw1 = agg_w[1], aw2 = agg_w[2], aw3 = agg_w[3];
    const float ab  = agg_b[0];

    auto p4_body = [&](int o, int pbeg, int pend) {
        const int c = o / 9, q = o - (o / 9) * 9;
        const int qi = q / 3, qj = q - (q / 3) * 3;
        const int qoff = (qi * R + qj) * CS + c;   // gather base (per o)
        float4 w0[8], w1[8];
        #pragma unroll
        for (int i = 0; i < 8; ++i) w0[i] = wp4[o * 16 + i];
        #pragma unroll
        for (int i = 0; i < 8; ++i) w1[i] = wp4[o * 16 + 8 + i];
        const float wb = wp_b[o];
        int py = pbeg / TS, px = pbeg - (pbeg / TS) * TS;
        #pragma unroll 1
        for (int p = pbeg; p < pend; ++p) {
            const float4* pc4 = (const float4*)(sC + ((py + 1) * S + (px + 1)) * CS);
            const float4* pa4 = (const float4*)(sA + ((py + M) * R + (px + M)) * CS);
            float4 a4 = make_float4(wb, 0.f, 0.f, 0.f);
            #pragma unroll
            for (int i = 0; i < 8; ++i) {
                float4 pv = pc4[i];
                a4.x += w0[i].x * pv.x; a4.y += w0[i].y * pv.y;
                a4.z += w0[i].z * pv.z; a4.w += w0[i].w * pv.w;
            }
            #pragma unroll
            for (int i = 0; i < 8; ++i) {
                float4 pv = pa4[i];
                a4.x += w1[i].x * pv.x; a4.y += w1[i].y * pv.y;
                a4.z += w1[i].z * pv.z; a4.w += w1[i].w * pv.w;
            }
            const float acc = (a4.x + a4.y) + (a4.z + a4.w);
            const int gbase = (py * R + px) * CS + qoff;     // + soff -> addr
            float aggd = ab;
            #pragma unroll
            for (int k = 0; k < 4; ++k) {
                int soff = sIdx[p * 4 + k];       // wave-uniform branch
                if (soff >= 0) {
                    float val = sA[gbase + soff];
                    float aw = (k == 0) ? aw0 : (k == 1) ? aw1 : (k == 2) ? aw2 : aw3;
                    aggd += aw * val;
                }
            }
            U[p * UST + o] = aggd * acc;
            if (++px == TS) { px = 0; ++py; }
        }
    };

    __builtin_amdgcn_s_setprio(1);
    p4_body(tid, 0, NP);                       // main: one o per thread
    {
        const int wv = tid >> 6, ln = tid & 63;
        if (wv >= 1 && ln < 32) {              // tail: waves 1..3, p-thirds
            const int pbeg = (NP * (wv - 1)) / 3;
            const int pend = (NP * wv) / 3;
            if (pbeg < pend) p4_body(256 + ln, pbeg, pend);
        }
    }
    __builtin_amdgcn_s_setprio(0);
    __syncthreads();

    // ---- P5: reduce over the 9 patch positions, store ----
    for (int e = tid; e < 32 * NP; e += 256) {
        int c = e / NP, p = e - (e / NP) * NP;
        int py = p / TS, px = p - (p / TS) * TS;
        float s = 0.f;
        const float* up = U + p * UST + c * 9;
        #pragma unroll
        for (int q = 0; q < 9; ++q) s += up[q];
        out[((t * 32 + c) * H + (y0 + py)) * W + (x0 + px)] = s;
    }
}

// jax.image.resize(method='linear') 2x: half-pixel centers, edge weights renorm
// to pure clamp. even o=2m: 0.25*x[m-1]+0.75*x[m]; odd o=2m+1: 0.75*x[m]+0.25*x[m+1].
// R22: one thread = even/odd x-PAIR (6 loads per pair, was 8; float2 store).
// Interp expression keeps the original wy*(wx*a+wx*b) ordering bit-for-bit.
__global__ void up2_kernel(const float* __restrict__ in, float* __restrict__ out,
                           int C, int h, int w)
{
    int idx = blockIdx.x * blockDim.x + threadIdx.x;  // one per output pair
    int H = 2 * h, W = 2 * w;
    int total = C * H * w;                            // w pairs per row
    if (idx >= total) return;
    int mx = idx % w;                                 // pair index = input col
    int oy = (idx / w) % H;
    int c  = idx / (w * H);

    int my = oy >> 1;
    int y0, y1;
    float wy0, wy1;
    if ((oy & 1) == 0) { y0 = max(my - 1, 0); y1 = my; wy0 = 0.25f; wy1 = 0.75f; }
    else               { y0 = my; y1 = min(my + 1, h - 1); wy0 = 0.75f; wy1 = 0.25f; }
    int xm = max(mx - 1, 0), xp = min(mx + 1, w - 1);

    const float* pc = in + (size_t)c * h * w;
    float r0m = pc[y0 * w + xm], r0c = pc[y0 * w + mx], r0p = pc[y0 * w + xp];
    float r1m = pc[y1 * w + xm], r1c = pc[y1 * w + mx], r1p = pc[y1 * w + xp];

    // even ox=2mx: wx0=0.25 @ xm, wx1=0.75 @ mx (original ordering)
    float ev = wy0 * (0.25f * r0m + 0.75f * r0c) + wy1 * (0.25f * r1m + 0.75f * r1c);
    // odd ox=2mx+1: wx0=0.75 @ mx, wx1=0.25 @ xp
    float od = wy0 * (0.75f * r0c + 0.25f * r0p) + wy1 * (0.75f * r1c + 0.25f * r1p);

    float2 v2 = make_float2(ev, od);
    *(float2*)&out[((size_t)c * H + oy) * W + 2 * mx] = v2;
}

// final: out128[o,y,x] = up_b[o] + sum_i up_w[o,i]*a1cat[i,y,x]; pixel_shuffle r=2.
// R22: 4 o's per block (one 2x2 shuffle quad) -> a1 L2 traffic /4; two
// coalesced float2 stores. Per-o FP order preserved: 4 partial chains per o
// (acc[o][u&3]) exactly as the old a0/a1p/a2p/a3p. Chunked loads kept (R20).
__global__ __launch_bounds__(256)
void final_kernel(const float* __restrict__ a1,   // (96, 48, 48)
                  const float* __restrict__ up_w, // (128, 96)
                  const float* __restrict__ up_b, // (128)
                  float* __restrict__ out)        // (32, 96, 96)
{
    const int pix = blockIdx.x * 256 + threadIdx.x;   // 0..2303
    const int ob  = blockIdx.y * 4;                   // 0,4,...,124 (uniform)
    const int x = pix % 48, y = pix / 48;

    const float* w0 = up_w + (ob + 0) * 96;
    const float* w1 = up_w + (ob + 1) * 96;
    const float* w2 = up_w + (ob + 2) * 96;
    const float* w3 = up_w + (ob + 3) * 96;
    float p0[4] = {up_b[ob + 0], 0.f, 0.f, 0.f};
    float p1[4] = {up_b[ob + 1], 0.f, 0.f, 0.f};
    float p2[4] = {up_b[ob + 2], 0.f, 0.f, 0.f};
    float p3[4] = {up_b[ob + 3], 0.f, 0.f, 0.f};
    #pragma unroll 1
    for (int i = 0; i < 96; i += 16) {
        float v[16];
        #pragma unroll
        for (int u = 0; u < 16; ++u) v[u] = a1[(size_t)(i + u) * 2304 + pix];
        #pragma unroll
        for (int u = 0; u < 16; ++u) {
            const int l = u & 3;
            p0[l] += w0[i + u] * v[u];
            p1[l] += w1[i + u] * v[u];
            p2[l] += w2[i + u] * v[u];
            p3[l] += w3[i + u] * v[u];
        }
    }
    float a0 = (p0[0] + p0[1]) + (p0[2] + p0[3]);
    float a1v = (p1[0] + p1[1]) + (p1[2] + p1[3]);
    float a2 = (p2[0] + p2[1]) + (p2[2] + p2[3]);
    float a3 = (p3[0] + p3[1]) + (p3[2] + p3[3]);

    // ob..ob+3 share co = ob>>2; (ry,rx) = (0,0),(0,1),(1,0),(1,1)
    const int co = ob >> 2;
    float* rowe = out + ((size_t)(co * 96 + 2 * y) * 96) + 2 * x;
    float* rowo = out + ((size_t)(co * 96 + 2 * y + 1) * 96) + 2 * x;
    *(float2*)rowe = make_float2(a0, a1v);
    *(float2*)rowo = make_float2(a2, a3);
}

extern "C" void kernel_launch(void* const* d_in, const int* in_sizes, int n_in,
                              void* d_out, int out_size, void* d_ws, size_t ws_size,
                              hipStream_t stream)
{
    const float* feats_l1 = (const float*)d_in[0];
    const float* feats_l2 = (const float*)d_in[1];
    const float* feats_l3 = (const float*)d_in[2];
    const float* agg_l3_w = (const float*)d_in[3];
    const float* agg_l3_b = (const float*)d_in[4];
    const float* wp_l3_w  = (const float*)d_in[5];
    const float* wp_l3_b  = (const float*)d_in[6];
    const float* agg_l2_w = (const float*)d_in[7];
    const float* agg_l2_b = (const float*)d_in[8];
    const float* wp_l2_w  = (const float*)d_in[9];
    const float* wp_l2_b  = (const float*)d_in[10];
    const float* agg_l1_w = (const float*)d_in[11];
    const float* agg_l1_b = (const float*)d_in[12];
    const float* wp_l1_w  = (const float*)d_in[13];
    const float* wp_l1_b  = (const float*)d_in[14];
    const float* up_w     = (const float*)d_in[15];
    const float* up_b     = (const float*)d_in[16];
    float* out = (float*)d_out;

    float* ws   = (float*)d_ws;
    float* agg3 = ws;                  // 3*32*12*12  = 13824
    float* a3up = agg3 + 13824;        // 3*32*24*24  = 55296
    float* agg2 = a3up + 55296;        // 3*32*24*24  = 55296
    float* a2up = agg2 + 55296;        // 3*32*48*48  = 221184
    float* a1   = a2up + 221184;       // 3*32*48*48  = 221184

    // level 3 (12x12, d=3), 1x1 tiles -> 144 x 3 = 432 blocks, no add
    agg_tile<3, 1, 12, 12, false><<<dim3(144, 3), 256, 0, stream>>>(
        feats_l3, nullptr, agg_l3_w, agg_l3_b, wp_l3_w, wp_l3_b, agg3);
    // paired-x up2: 96*24*12 = 27648 pairs
    up2_kernel<<<(96 * 24 * 12 + 255) / 256, 256, 0, stream>>>(agg3, a3up, 96, 12, 12);

    // level 2 (24x24, d=5), 2x2 tiles -> 144 x 3 = 432 blocks
    agg_tile<5, 2, 24, 24, true><<<dim3(144, 3), 256, 0, stream>>>(
        feats_l2, a3up, agg_l2_w, agg_l2_b, wp_l2_w, wp_l2_b, agg2);
    // paired-x up2: 96*48*24 = 110592 pairs
    up2_kernel<<<(96 * 48 * 24 + 255) / 256, 256, 0, stream>>>(agg2, a2up, 96, 24, 24);

    // level 1 (48x48, d=7), 3x3 tiles -> 256 x 3 = 768 blocks (= 3/CU)
    agg_tile<7, 3, 48, 48, true><<<dim3(256, 3), 256, 0, stream>>>(
        feats_l1, a2up, agg_l1_w, agg_l1_b, wp_l1_w, wp_l1_b, a1);

    // final projection + pixel shuffle: 4 o's (one shuffle quad) per block
    final_kernel<<<dim3(9, 32), 256, 0, stream>>>(a1, up_w, up_b, out);
}

// Round 9
// 150.810 us; speedup vs baseline: 1.0008x; 1.0008x over previous
//
#include <hip/hip_runtime.h>
#include <math.h>

// ---------------------------------------------------------------------------
// TMCAM, R24 = R21 champion (148.7us) + up2 x-pairing ONLY (isolation round).
// R23 post-mortem: R22 bundle (final 4-o + up2 pair) = 150.9 (+2.2 vs champ,
// ~noise edge). Suspect mechanism: final 4-o cut grid 1152->288 blocks
// (1.1/CU, single block-wave; wall = per-block serial chunk chain; 4x FMA
// per thread) — L2-traffic saving was outweighed by parallelism loss.
// up2 pairing has no harm mechanism (same scheme, fewer loads, float2 store).
// R24 isolates it: final_kernel reverted to the R20/R21 128-o version.
// Decision rule: ~147-149 -> keep (final-4o was the regression);
// >=150.5 -> up2 pair harmful, full revert to R21 and declare plateau.
// NOTE: agg kernels now run below the 40us harness fills -> invisible in
// top-5 counters; single-variable rounds mandatory.
// Ledger of banned moves (all measured): grid.sync (R10); fused-up2-in-
// staging (R6); P4 full p-loop unroll (R2/R7 spill); small tiles (R9); P4
// unit remap (R13/R14); OSPLIT (R16); 5-wave blocks w/ tight launch_bounds
// (R19, spill = WRITE_SIZE explosion at LOW VGPR); final 4-o blocking (R23).
// ---------------------------------------------------------------------------

template<int D, int TS, int H, int W, bool HA>
__global__ __launch_bounds__(256, 3)
void agg_tile(const float* __restrict__ feats,   // (32, 3, H, W)
              const float* __restrict__ add,     // (3, 32, H, W) or null
              const float* __restrict__ agg_w,   // (4)
              const float* __restrict__ agg_b,   // (1)
              const float* __restrict__ wp_w,    // (288, 64) row-major
              const float* __restrict__ wp_b,    // (288)
              float* __restrict__ out)           // (3, 32, H, W)
{
    constexpr int PD = D / 2;
    constexpr int M  = PD + 1;            // stage margin (disp + 3x3 unfold)
    constexpr int R  = TS + 2 * M;        // sA region edge
    constexpr int S  = TS + 2;            // sC region edge
    constexpr int S2 = S * S;
    constexpr int D2 = D * D;
    constexpr int NP = TS * TS;
    constexpr int NX = S2 * D2;
    constexpr int NSIM = NP * D2;
    constexpr int CS = 36;                // padded per-pos float stride
    constexpr int UST = 292;              // U row stride (292 % 32 = 4: no
                                          // 9-way P5 bank conflict like 288)
    constexpr int USZ = (NP * UST > NX + NSIM) ? NP * UST : NX + NSIM;
    constexpr int TPW = W / TS;
    constexpr int NPA = R * R;
    constexpr int GA  = 256 / NPA;        // channel groups for sA staging
    constexpr int NPS = S * S;
    constexpr int GS  = 256 / NPS;
    constexpr int NITA = (32 + GA - 1) / GA;  // channel iters per sA thread
    constexpr int NITS = (32 + GS - 1) / GS;  // channel iters per sC thread

    __shared__ float sA[NPA * CS];        // feat_tm1 (+add), [pos][c]
    __shared__ float sC[NPS * CS];        // feat_t center (+add), [pos][c]
    __shared__ float t2[NPA];             // sum_c sA^2 per pos
    __shared__ float s2[NPS];             // sum_c sC^2 per pos
    __shared__ float U[USZ];              // X | sSim, then final product
    __shared__ int   sIdx[NP * 4];        // top-4 sA offsets (pre-scaled) or -1

    float* Xarr = U;                      // NX entries, [u*D2+dd]
    float* sSim = U + NX;                 // NSIM entries

    const int tid  = threadIdx.x;
    const int tile = blockIdx.x;
    const int t    = blockIdx.y;
    const int y0 = (tile / TPW) * TS;
    const int x0 = (tile % TPW) * TS;

    const float* addT = HA ? (add + (size_t)t * 32 * H * W) : nullptr;

    // ---- P0: stage sA (frame t + add) / sC (frame 1 + add). Chunked
    //      reg-buffered: 8 channel loads in flight, then 8 LDS writes
    //      (kills the unroll-1 load->write serial latency chain). ----
    if (tid < NPA * GA) {
        const int pos = tid % NPA;
        const int cb  = tid / NPA;
        const int ry = pos / R, rx = pos % R;
        const int yy = y0 - M + ry, xx = x0 - M + rx;
        float* dst = sA + pos * CS;
        if (yy >= 0 && yy < H && xx >= 0 && xx < W) {
            const float* sF = feats + (((size_t)cb * 3 + t) * H + yy) * W + xx;
            const float* sD = HA ? (addT + ((size_t)cb * H + yy) * W + xx) : nullptr;
            #pragma unroll 1
            for (int kb = 0; kb < NITA; kb += 8) {
                float v[8];
                #pragma unroll
                for (int u = 0; u < 8; ++u) {
                    const int k = kb + u;
                    const int c = cb + k * GA;
                    if (k < NITA && c < 32) {
                        float x = sF[(size_t)k * GA * 3 * H * W];
                        if (HA) x += sD[(size_t)k * GA * H * W];
                        v[u] = x;
                    }
                }
                #pragma unroll
                for (int u = 0; u < 8; ++u) {
                    const int k = kb + u;
                    const int c = cb + k * GA;
                    if (k < NITA && c < 32) dst[c] = v[u];
                }
            }
        } else {
            #pragma unroll 1
            for (int c = cb; c < 32; c += GA) dst[c] = 0.f;
        }
    }
    if (tid < NPS * GS) {
        const int pos = tid % NPS;
        const int cb  = tid / NPS;
        const int ry = pos / S, rx = pos % S;
        const int yy = y0 - 1 + ry, xx = x0 - 1 + rx;
        float* dst = sC + pos * CS;
        if (yy >= 0 && yy < H && xx >= 0 && xx < W) {
            const float* sF = feats + (((size_t)cb * 3 + 1) * H + yy) * W + xx;
            const float* sD = HA ? (addT + ((size_t)cb * H + yy) * W + xx) : nullptr;
            #pragma unroll 1
            for (int kb = 0; kb < NITS; kb += 8) {
                float v[8];
                #pragma unroll
                for (int u = 0; u < 8; ++u) {
                    const int k = kb + u;
                    const int c = cb + k * GS;
                    if (k < NITS && c < 32) {
                        float x = sF[(size_t)k * GS * 3 * H * W];
                        if (HA) x += sD[(size_t)k * GS * H * W];
                        v[u] = x;
                    }
                }
                #pragma unroll
                for (int u = 0; u < 8; ++u) {
                    const int k = kb + u;
                    const int c = cb + k * GS;
                    if (k < NITS && c < 32) dst[c] = v[u];
                }
            }
        } else {
            #pragma unroll 1
            for (int c = cb; c < 32; c += GS) dst[c] = 0.f;
        }
    }
    __syncthreads();

    // ---- P1: X (thread = (u,di), sC row cached in regs, D indep dj dots
    //      -> cross-dj ILP already), t2, s2 ----
    if (tid < S2 * D) {
        const int u  = tid / D;
        const int di = tid - u * D;
        const int uy = u / S, ux = u - uy * S;
        float4 cv[8];
        const float4* c4 = (const float4*)(sC + u * CS);
        #pragma unroll
        for (int i = 0; i < 8; ++i) cv[i] = c4[i];
        const float* arow = sA + ((uy + di) * R + ux) * CS;
        float* xrow = Xarr + u * D2 + di * D;
        #pragma unroll
        for (int dj = 0; dj < D; ++dj) {
            const float4* a4 = (const float4*)(arow + dj * CS);
            float s = 0.f;
            #pragma unroll
            for (int i = 0; i < 8; ++i) {
                float4 av = a4[i];
                s += cv[i].x * av.x + cv[i].y * av.y + cv[i].z * av.z + cv[i].w * av.w;
            }
            xrow[dj] = s;
        }
    }
    for (int e = tid; e < NPA; e += 256) {
        const float4* a4 = (const float4*)(sA + e * CS);
        float4 s4 = make_float4(0.f, 0.f, 0.f, 0.f);
        #pragma unroll
        for (int cc = 0; cc < 8; ++cc) {
            float4 v = a4[cc];
            s4.x += v.x * v.x; s4.y += v.y * v.y;
            s4.z += v.z * v.z; s4.w += v.w * v.w;
        }
        t2[e] = (s4.x + s4.y) + (s4.z + s4.w);
    }
    for (int e = tid; e < NPS; e += 256) {
        const float4* c4 = (const float4*)(sC + e * CS);
        float4 s4 = make_float4(0.f, 0.f, 0.f, 0.f);
        #pragma unroll
        for (int cc = 0; cc < 8; ++cc) {
            float4 v = c4[cc];
            s4.x += v.x * v.x; s4.y += v.y * v.y;
            s4.z += v.z * v.z; s4.w += v.w * v.w;
        }
        s2[e] = (s4.x + s4.y) + (s4.z + s4.w);
    }
    __syncthreads();

    // ---- P2: sims (mask out-of-image displaced centers to exactly 0) ----
    for (int e = tid; e < NSIM; e += 256) {
        int p = e / D2, dd = e - p * D2;
        int py = p / TS, px = p - py * TS;
        int di = dd / D, dj = dd - di * D;
        int Yc = y0 + py + di - PD, Xc = x0 + px + dj - PD;
        float sim = 0.f;
        if (Yc >= 0 && Yc < H && Xc >= 0 && Xc < W) {
            float dot = 0.f, n2 = 0.f, nf = 0.f;
            #pragma unroll
            for (int qi = 0; qi < 3; ++qi)
            #pragma unroll
            for (int qj = 0; qj < 3; ++qj) {
                dot += Xarr[((py + qi) * S + (px + qj)) * D2 + dd];
                n2  += t2[(py + qi + di) * R + (px + qj + dj)];
                nf  += s2[(py + qi) * S + (px + qj)];
            }
            sim = dot / fmaxf(sqrtf(nf), 1e-12f) / fmaxf(sqrtf(n2), 1e-12f);
        }
        sSim[e] = sim;
    }
    __syncthreads();

    // ---- P3: per-pixel top-4 (strict-insert == stable ties, lax.top_k);
    //      store pre-scaled sA offsets ----
    if (tid < NP) {
        float v0 = -3.0e38f, v1 = -3.0e38f, v2 = -3.0e38f, v3 = -3.0e38f;
        int   i0 = 0, i1 = 0, i2 = 0, i3 = 0;
        const float* row = sSim + tid * D2;
        for (int dd = 0; dd < D2; ++dd) {
            float v = row[dd];
            if (v > v0)      { v3=v2;i3=i2; v2=v1;i2=i1; v1=v0;i1=i0; v0=v;i0=dd; }
            else if (v > v1) { v3=v2;i3=i2; v2=v1;i2=i1; v1=v;i1=dd; }
            else if (v > v2) { v3=v2;i3=i2; v2=v;i2=dd; }
            else if (v > v3) { v3=v;i3=dd; }
        }
        int py = tid / TS, px = tid - (tid / TS) * TS;
        int ids[4] = {i0, i1, i2, i3};
        #pragma unroll
        for (int k = 0; k < 4; ++k) {
            int dd = ids[k];
            int di = dd / D, dj = dd - di * D;
            int Yc = y0 + py + di - PD, Xc = x0 + px + dj - PD;
            sIdx[tid * 4 + k] = (Yc >= 0 && Yc < H && Xc >= 0 && Xc < W)
                              ? (di * R + dj) * CS : -1;
        }
    }
    __syncthreads();

    // ---- P4 (fused): both wm halves + aggd gather + multiply in ONE pass.
    //      Main: each thread does exactly one o = tid. Tail o in [256,288):
    //      lanes 0-31 of waves 1/2/3, each covering 1/3 of the p-range
    //      (critical path ~960 insts vs the old wave-0 double sweep ~1440).
    //      setprio(1) favors P4 waves over other blocks' staging (T5). ----
    const float4* wp4 = (const float4*)wp_w;
    const float aw0 = agg_w[0], aw1 = agg_w[1], aw2 = agg_w[2], aw3 = agg_w[3];
    const float ab  = agg_b[0];

    auto p4_body = [&](int o, int pbeg, int pend) {
        const int c = o / 9, q = o - (o / 9) * 9;
        const int qi = q / 3, qj = q - (q / 3) * 3;
        const int qoff = (qi * R + qj) * CS + c;   // gather base (per o)
        float4 w0[8], w1[8];
        #pragma unroll
        for (int i = 0; i < 8; ++i) w0[i] = wp4[o * 16 + i];
        #pragma unroll
        for (int i = 0; i < 8; ++i) w1[i] = wp4[o * 16 + 8 + i];
        const float wb = wp_b[o];
        int py = pbeg / TS, px = pbeg - (pbeg / TS) * TS;
        #pragma unroll 1
        for (int p = pbeg; p < pend; ++p) {
            const float4* pc4 = (const float4*)(sC + ((py + 1) * S + (px + 1)) * CS);
            const float4* pa4 = (const float4*)(sA + ((py + M) * R + (px + M)) * CS);
            float4 a4 = make_float4(wb, 0.f, 0.f, 0.f);
            #pragma unroll
            for (int i = 0; i < 8; ++i) {
                float4 pv = pc4[i];
                a4.x += w0[i].x * pv.x; a4.y += w0[i].y * pv.y;
                a4.z += w0[i].z * pv.z; a4.w += w0[i].w * pv.w;
            }
            #pragma unroll
            for (int i = 0; i < 8; ++i) {
                float4 pv = pa4[i];
                a4.x += w1[i].x * pv.x; a4.y += w1[i].y * pv.y;
                a4.z += w1[i].z * pv.z; a4.w += w1[i].w * pv.w;
            }
            const float acc = (a4.x + a4.y) + (a4.z + a4.w);
            const int gbase = (py * R + px) * CS + qoff;     // + soff -> addr
            float aggd = ab;
            #pragma unroll
            for (int k = 0; k < 4; ++k) {
                int soff = sIdx[p * 4 + k];       // wave-uniform branch
                if (soff >= 0) {
                    float val = sA[gbase + soff];
                    float aw = (k == 0) ? aw0 : (k == 1) ? aw1 : (k == 2) ? aw2 : aw3;
                    aggd += aw * val;
                }
            }
            U[p * UST + o] = aggd * acc;
            if (++px == TS) { px = 0; ++py; }
        }
    };

    __builtin_amdgcn_s_setprio(1);
    p4_body(tid, 0, NP);                       // main: one o per thread
    {
        const int wv = tid >> 6, ln = tid & 63;
        if (wv >= 1 && ln < 32) {              // tail: waves 1..3, p-thirds
            const int pbeg = (NP * (wv - 1)) / 3;
            const int pend = (NP * wv) / 3;
            if (pbeg < pend) p4_body(256 + ln, pbeg, pend);
        }
    }
    __builtin_amdgcn_s_setprio(0);
    __syncthreads();

    // ---- P5: reduce over the 9 patch positions, store ----
    for (int e = tid; e < 32 * NP; e += 256) {
        int c = e / NP, p = e - (e / NP) * NP;
        int py = p / TS, px = p - (p / TS) * TS;
        float s = 0.f;
        const float* up = U + p * UST + c * 9;
        #pragma unroll
        for (int q = 0; q < 9; ++q) s += up[q];
        out[((t * 32 + c) * H + (y0 + py)) * W + (x0 + px)] = s;
    }
}

// jax.image.resize(method='linear') 2x: half-pixel centers, edge weights renorm
// to pure clamp. even o=2m: 0.25*x[m-1]+0.75*x[m]; odd o=2m+1: 0.75*x[m]+0.25*x[m+1].
// R24 (kept from R22): one thread = even/odd x-PAIR (6 loads per pair, was 8;
// float2 store). Interp keeps the original wy*(wx*a+wx*b) ordering bit-for-bit.
__global__ void up2_kernel(const float* __restrict__ in, float* __restrict__ out,
                           int C, int h, int w)
{
    int idx = blockIdx.x * blockDim.x + threadIdx.x;  // one per output pair
    int H = 2 * h, W = 2 * w;
    int total = C * H * w;                            // w pairs per row
    if (idx >= total) return;
    int mx = idx % w;                                 // pair index = input col
    int oy = (idx / w) % H;
    int c  = idx / (w * H);

    int my = oy >> 1;
    int y0, y1;
    float wy0, wy1;
    if ((oy & 1) == 0) { y0 = max(my - 1, 0); y1 = my; wy0 = 0.25f; wy1 = 0.75f; }
    else               { y0 = my; y1 = min(my + 1, h - 1); wy0 = 0.75f; wy1 = 0.25f; }
    int xm = max(mx - 1, 0), xp = min(mx + 1, w - 1);

    const float* pc = in + (size_t)c * h * w;
    float r0m = pc[y0 * w + xm], r0c = pc[y0 * w + mx], r0p = pc[y0 * w + xp];
    float r1m = pc[y1 * w + xm], r1c = pc[y1 * w + mx], r1p = pc[y1 * w + xp];

    // even ox=2mx: wx0=0.25 @ xm, wx1=0.75 @ mx (original ordering)
    float ev = wy0 * (0.25f * r0m + 0.75f * r0c) + wy1 * (0.25f * r1m + 0.75f * r1c);
    // odd ox=2mx+1: wx0=0.75 @ mx, wx1=0.25 @ xp
    float od = wy0 * (0.75f * r0c + 0.25f * r0p) + wy1 * (0.75f * r1c + 0.25f * r1p);

    float2 v2 = make_float2(ev, od);
    *(float2*)&out[((size_t)c * H + oy) * W + 2 * mx] = v2;
}

// final: out128[o,y,x] = up_b[o] + sum_i up_w[o,i]*a1cat[i,y,x]; pixel_shuffle r=2.
// o from blockIdx.y -> weight reads scalar, a1 reads coalesced.
// R24: REVERTED to the R20/R21 128-o-block version (R23's 4-o blocking cut
// the grid to 288 blocks = 1.1/CU and regressed). Chunked loads kept.
__global__ __launch_bounds__(256)
void final_kernel(const float* __restrict__ a1,   // (96, 48, 48)
                  const float* __restrict__ up_w, // (128, 96)
                  const float* __restrict__ up_b, // (128)
                  float* __restrict__ out)        // (32, 96, 96)
{
    const int pix = blockIdx.x * 256 + threadIdx.x;   // 0..2303
    const int o   = blockIdx.y;                       // 0..127 (uniform)
    const int x = pix % 48, y = pix / 48;

    const float* w = up_w + o * 96;
    float a0 = up_b[o], a1p = 0.f, a2p = 0.f, a3p = 0.f;
    #pragma unroll 1
    for (int i = 0; i < 96; i += 16) {
        float v[16];
        #pragma unroll
        for (int u = 0; u < 16; ++u) v[u] = a1[(size_t)(i + u) * 2304 + pix];
        #pragma unroll
        for (int u = 0; u < 16; u += 4) {
            a0  += w[i + u]     * v[u];
            a1p += w[i + u + 1] * v[u + 1];
            a2p += w[i + u + 2] * v[u + 2];
            a3p += w[i + u + 3] * v[u + 3];
        }
    }
    float acc = (a0 + a1p) + (a2p + a3p);

    int co = o >> 2, ry = (o >> 1) & 1, rx = o & 1;
    out[((co * 96 + 2 * y + ry) * 96) + 2 * x + rx] = acc;
}

extern "C" void kernel_launch(void* const* d_in, const int* in_sizes, int n_in,
                              void* d_out, int out_size, void* d_ws, size_t ws_size,
                              hipStream_t stream)
{
    const float* feats_l1 = (const float*)d_in[0];
    const float* feats_l2 = (const float*)d_in[1];
    const float* feats_l3 = (const float*)d_in[2];
    const float* agg_l3_w = (const float*)d_in[3];
    const float* agg_l3_b = (const float*)d_in[4];
    const float* wp_l3_w  = (const float*)d_in[5];
    const float* wp_l3_b  = (const float*)d_in[6];
    const float* agg_l2_w = (const float*)d_in[7];
    const float* agg_l2_b = (const float*)d_in[8];
    const float* wp_l2_w  = (const float*)d_in[9];
    const float* wp_l2_b  = (const float*)d_in[10];
    const float* agg_l1_w = (const float*)d_in[11];
    const float* agg_l1_b = (const float*)d_in[12];
    const float* wp_l1_w  = (const float*)d_in[13];
    const float* wp_l1_b  = (const float*)d_in[14];
    const float* up_w     = (const float*)d_in[15];
    const float* up_b     = (const float*)d_in[16];
    float* out = (float*)d_out;

    float* ws   = (float*)d_ws;
    float* agg3 = ws;                  // 3*32*12*12  = 13824
    float* a3up = agg3 + 13824;        // 3*32*24*24  = 55296
    float* agg2 = a3up + 55296;        // 3*32*24*24  = 55296
    float* a2up = agg2 + 55296;        // 3*32*48*48  = 221184
    float* a1   = a2up + 221184;       // 3*32*48*48  = 221184

    // level 3 (12x12, d=3), 1x1 tiles -> 144 x 3 = 432 blocks, no add
    agg_tile<3, 1, 12, 12, false><<<dim3(144, 3), 256, 0, stream>>>(
        feats_l3, nullptr, agg_l3_w, agg_l3_b, wp_l3_w, wp_l3_b, agg3);
    // paired-x up2: 96*24*12 = 27648 pairs
    up2_kernel<<<(96 * 24 * 12 + 255) / 256, 256, 0, stream>>>(agg3, a3up, 96, 12, 12);

    // level 2 (24x24, d=5), 2x2 tiles -> 144 x 3 = 432 blocks
    agg_tile<5, 2, 24, 24, true><<<dim3(144, 3), 256, 0, stream>>>(
        feats_l2, a3up, agg_l2_w, agg_l2_b, wp_l2_w, wp_l2_b, agg2);
    // paired-x up2: 96*48*24 = 110592 pairs
    up2_kernel<<<(96 * 48 * 24 + 255) / 256, 256, 0, stream>>>(agg2, a2up, 96, 24, 24);

    // level 1 (48x48, d=7), 3x3 tiles -> 256 x 3 = 768 blocks (= 3/CU)
    agg_tile<7, 3, 48, 48, true><<<dim3(256, 3), 256, 0, stream>>>(
        feats_l1, a2up, agg_l1_w, agg_l1_b, wp_l1_w, wp_l1_b, a1);

    // final projection + pixel shuffle (o uniform per block -> scalar weights)
    final_kernel<<<dim3(9, 128), 256, 0, stream>>>(a1, up_w, up_b, out);
}

// Round 10
// 148.249 us; speedup vs baseline: 1.0181x; 1.0173x over previous
//
#include <hip/hip_runtime.h>
#include <math.h>

// ---------------------------------------------------------------------------
// TMCAM, R25 = R21 verbatim (champion restore, 148.7us).
// R24 post-mortem: up2 x-pairing isolated as harmful (+2.1us; R23=150.9,
// R24=150.8, consistent). Mechanism: halved thread count of tiny latency-
// bound kernels (l3-up2 216->108 blocks = 0.42/CU) to save parallel-issued
// loads — wrong currency. Same failure class as R23's final-4o.
// SESSION LAW (final form): parallelism at fixed work beats work-reduction
// at reduced parallelism (R16/R19/R23/R24 regress vs R17/R20/R21 win).
// Serial-latency-chain removals pay; work-shuffles neutral; occupancy and
// work-consolidation bets regress.
// Ledger of banned moves (all measured): grid.sync (R10); fused-up2-in-
// staging (R6); P4 full p-loop unroll (R2/R7 spill); small tiles (R9); P4
// unit remap (R13/R14); OSPLIT (R16); 5-wave blocks w/ tight launch_bounds
// (R19, spill = WRITE_SIZE explosion at LOW VGPR); final 4-o blocking (R23);
// up2 x-pairing (R24).
// Remaining structure: agg barrier-convoy bound (VALU 23%, HBM 3%, no
// saturated pipe); all escapes measured-banned; residual deltas < +-2us
// session noise. Plateau declaration expected next round if ~148.7 confirms.
// ---------------------------------------------------------------------------

template<int D, int TS, int H, int W, bool HA>
__global__ __launch_bounds__(256, 3)
void agg_tile(const float* __restrict__ feats,   // (32, 3, H, W)
              const float* __restrict__ add,     // (3, 32, H, W) or null
              const float* __restrict__ agg_w,   // (4)
              const float* __restrict__ agg_b,   // (1)
              const float* __restrict__ wp_w,    // (288, 64) row-major
              const float* __restrict__ wp_b,    // (288)
              float* __restrict__ out)           // (3, 32, H, W)
{
    constexpr int PD = D / 2;
    constexpr int M  = PD + 1;            // stage margin (disp + 3x3 unfold)
    constexpr int R  = TS + 2 * M;        // sA region edge
    constexpr int S  = TS + 2;            // sC region edge
    constexpr int S2 = S * S;
    constexpr int D2 = D * D;
    constexpr int NP = TS * TS;
    constexpr int NX = S2 * D2;
    constexpr int NSIM = NP * D2;
    constexpr int CS = 36;                // padded per-pos float stride
    constexpr int UST = 292;              // U row stride (292 % 32 = 4: no
                                          // 9-way P5 bank conflict like 288)
    constexpr int USZ = (NP * UST > NX + NSIM) ? NP * UST : NX + NSIM;
    constexpr int TPW = W / TS;
    constexpr int NPA = R * R;
    constexpr int GA  = 256 / NPA;        // channel groups for sA staging
    constexpr int NPS = S * S;
    constexpr int GS  = 256 / NPS;
    constexpr int NITA = (32 + GA - 1) / GA;  // channel iters per sA thread
    constexpr int NITS = (32 + GS - 1) / GS;  // channel iters per sC thread

    __shared__ float sA[NPA * CS];        // feat_tm1 (+add), [pos][c]
    __shared__ float sC[NPS * CS];        // feat_t center (+add), [pos][c]
    __shared__ float t2[NPA];             // sum_c sA^2 per pos
    __shared__ float s2[NPS];             // sum_c sC^2 per pos
    __shared__ float U[USZ];              // X | sSim, then final product
    __shared__ int   sIdx[NP * 4];        // top-4 sA offsets (pre-scaled) or -1

    float* Xarr = U;                      // NX entries, [u*D2+dd]
    float* sSim = U + NX;                 // NSIM entries

    const int tid  = threadIdx.x;
    const int tile = blockIdx.x;
    const int t    = blockIdx.y;
    const int y0 = (tile / TPW) * TS;
    const int x0 = (tile % TPW) * TS;

    const float* addT = HA ? (add + (size_t)t * 32 * H * W) : nullptr;

    // ---- P0: stage sA (frame t + add) / sC (frame 1 + add). Chunked
    //      reg-buffered: 8 channel loads in flight, then 8 LDS writes
    //      (kills the unroll-1 load->write serial latency chain). ----
    if (tid < NPA * GA) {
        const int pos = tid % NPA;
        const int cb  = tid / NPA;
        const int ry = pos / R, rx = pos % R;
        const int yy = y0 - M + ry, xx = x0 - M + rx;
        float* dst = sA + pos * CS;
        if (yy >= 0 && yy < H && xx >= 0 && xx < W) {
            const float* sF = feats + (((size_t)cb * 3 + t) * H + yy) * W + xx;
            const float* sD = HA ? (addT + ((size_t)cb * H + yy) * W + xx) : nullptr;
            #pragma unroll 1
            for (int kb = 0; kb < NITA; kb += 8) {
                float v[8];
                #pragma unroll
                for (int u = 0; u < 8; ++u) {
                    const int k = kb + u;
                    const int c = cb + k * GA;
                    if (k < NITA && c < 32) {
                        float x = sF[(size_t)k * GA * 3 * H * W];
                        if (HA) x += sD[(size_t)k * GA * H * W];
                        v[u] = x;
                    }
                }
                #pragma unroll
                for (int u = 0; u < 8; ++u) {
                    const int k = kb + u;
                    const int c = cb + k * GA;
                    if (k < NITA && c < 32) dst[c] = v[u];
                }
            }
        } else {
            #pragma unroll 1
            for (int c = cb; c < 32; c += GA) dst[c] = 0.f;
        }
    }
    if (tid < NPS * GS) {
        const int pos = tid % NPS;
        const int cb  = tid / NPS;
        const int ry = pos / S, rx = pos % S;
        const int yy = y0 - 1 + ry, xx = x0 - 1 + rx;
        float* dst = sC + pos * CS;
        if (yy >= 0 && yy < H && xx >= 0 && xx < W) {
            const float* sF = feats + (((size_t)cb * 3 + 1) * H + yy) * W + xx;
            const float* sD = HA ? (addT + ((size_t)cb * H + yy) * W + xx) : nullptr;
            #pragma unroll 1
            for (int kb = 0; kb < NITS; kb += 8) {
                float v[8];
                #pragma unroll
                for (int u = 0; u < 8; ++u) {
                    const int k = kb + u;
                    const int c = cb + k * GS;
                    if (k < NITS && c < 32) {
                        float x = sF[(size_t)k * GS * 3 * H * W];
                        if (HA) x += sD[(size_t)k * GS * H * W];
                        v[u] = x;
                    }
                }
                #pragma unroll
                for (int u = 0; u < 8; ++u) {
                    const int k = kb + u;
                    const int c = cb + k * GS;
                    if (k < NITS && c < 32) dst[c] = v[u];
                }
            }
        } else {
            #pragma unroll 1
            for (int c = cb; c < 32; c += GS) dst[c] = 0.f;
        }
    }
    __syncthreads();

    // ---- P1: X (thread = (u,di), sC row cached in regs, D indep dj dots
    //      -> cross-dj ILP already), t2, s2 ----
    if (tid < S2 * D) {
        const int u  = tid / D;
        const int di = tid - u * D;
        const int uy = u / S, ux = u - uy * S;
        float4 cv[8];
        const float4* c4 = (const float4*)(sC + u * CS);
        #pragma unroll
        for (int i = 0; i < 8; ++i) cv[i] = c4[i];
        const float* arow = sA + ((uy + di) * R + ux) * CS;
        float* xrow = Xarr + u * D2 + di * D;
        #pragma unroll
        for (int dj = 0; dj < D; ++dj) {
            const float4* a4 = (const float4*)(arow + dj * CS);
            float s = 0.f;
            #pragma unroll
            for (int i = 0; i < 8; ++i) {
                float4 av = a4[i];
                s += cv[i].x * av.x + cv[i].y * av.y + cv[i].z * av.z + cv[i].w * av.w;
            }
            xrow[dj] = s;
        }
    }
    for (int e = tid; e < NPA; e += 256) {
        const float4* a4 = (const float4*)(sA + e * CS);
        float4 s4 = make_float4(0.f, 0.f, 0.f, 0.f);
        #pragma unroll
        for (int cc = 0; cc < 8; ++cc) {
            float4 v = a4[cc];
            s4.x += v.x * v.x; s4.y += v.y * v.y;
            s4.z += v.z * v.z; s4.w += v.w * v.w;
        }
        t2[e] = (s4.x + s4.y) + (s4.z + s4.w);
    }
    for (int e = tid; e < NPS; e += 256) {
        const float4* c4 = (const float4*)(sC + e * CS);
        float4 s4 = make_float4(0.f, 0.f, 0.f, 0.f);
        #pragma unroll
        for (int cc = 0; cc < 8; ++cc) {
            float4 v = c4[cc];
            s4.x += v.x * v.x; s4.y += v.y * v.y;
            s4.z += v.z * v.z; s4.w += v.w * v.w;
        }
        s2[e] = (s4.x + s4.y) + (s4.z + s4.w);
    }
    __syncthreads();

    // ---- P2: sims (mask out-of-image displaced centers to exactly 0) ----
    for (int e = tid; e < NSIM; e += 256) {
        int p = e / D2, dd = e - p * D2;
        int py = p / TS, px = p - py * TS;
        int di = dd / D, dj = dd - di * D;
        int Yc = y0 + py + di - PD, Xc = x0 + px + dj - PD;
        float sim = 0.f;
        if (Yc >= 0 && Yc < H && Xc >= 0 && Xc < W) {
            float dot = 0.f, n2 = 0.f, nf = 0.f;
            #pragma unroll
            for (int qi = 0; qi < 3; ++qi)
            #pragma unroll
            for (int qj = 0; qj < 3; ++qj) {
                dot += Xarr[((py + qi) * S + (px + qj)) * D2 + dd];
                n2  += t2[(py + qi + di) * R + (px + qj + dj)];
                nf  += s2[(py + qi) * S + (px + qj)];
            }
            sim = dot / fmaxf(sqrtf(nf), 1e-12f) / fmaxf(sqrtf(n2), 1e-12f);
        }
        sSim[e] = sim;
    }
    __syncthreads();

    // ---- P3: per-pixel top-4 (strict-insert == stable ties, lax.top_k);
    //      store pre-scaled sA offsets ----
    if (tid < NP) {
        float v0 = -3.0e38f, v1 = -3.0e38f, v2 = -3.0e38f, v3 = -3.0e38f;
        int   i0 = 0, i1 = 0, i2 = 0, i3 = 0;
        const float* row = sSim + tid * D2;
        for (int dd = 0; dd < D2; ++dd) {
            float v = row[dd];
            if (v > v0)      { v3=v2;i3=i2; v2=v1;i2=i1; v1=v0;i1=i0; v0=v;i0=dd; }
            else if (v > v1) { v3=v2;i3=i2; v2=v1;i2=i1; v1=v;i1=dd; }
            else if (v > v2) { v3=v2;i3=i2; v2=v;i2=dd; }
            else if (v > v3) { v3=v;i3=dd; }
        }
        int py = tid / TS, px = tid - (tid / TS) * TS;
        int ids[4] = {i0, i1, i2, i3};
        #pragma unroll
        for (int k = 0; k < 4; ++k) {
            int dd = ids[k];
            int di = dd / D, dj = dd - di * D;
            int Yc = y0 + py + di - PD, Xc = x0 + px + dj - PD;
            sIdx[tid * 4 + k] = (Yc >= 0 && Yc < H && Xc >= 0 && Xc < W)
                              ? (di * R + dj) * CS : -1;
        }
    }
    __syncthreads();

    // ---- P4 (fused): both wm halves + aggd gather + multiply in ONE pass.
    //      Main: each thread does exactly one o = tid. Tail o in [256,288):
    //      lanes 0-31 of waves 1/2/3, each covering 1/3 of the p-range
    //      (critical path ~960 insts vs the old wave-0 double sweep ~1440).
    //      setprio(1) favors P4 waves over other blocks' staging (T5). ----
    const float4* wp4 = (const float4*)wp_w;
    const float aw0 = agg_w[0], aw1 = agg_w[1], aw2 = agg_w[2], aw3 = agg_w[3];
    const float ab  = agg_b[0];

    auto p4_body = [&](int o, int pbeg, int pend) {
        const int c = o / 9, q = o - (o / 9) * 9;
        const int qi = q / 3, qj = q - (q / 3) * 3;
        const int qoff = (qi * R + qj) * CS + c;   // gather base (per o)
        float4 w0[8], w1[8];
        #pragma unroll
        for (int i = 0; i < 8; ++i) w0[i] = wp4[o * 16 + i];
        #pragma unroll
        for (int i = 0; i < 8; ++i) w1[i] = wp4[o * 16 + 8 + i];
        const float wb = wp_b[o];
        int py = pbeg / TS, px = pbeg - (pbeg / TS) * TS;
        #pragma unroll 1
        for (int p = pbeg; p < pend; ++p) {
            const float4* pc4 = (const float4*)(sC + ((py + 1) * S + (px + 1)) * CS);
            const float4* pa4 = (const float4*)(sA + ((py + M) * R + (px + M)) * CS);
            float4 a4 = make_float4(wb, 0.f, 0.f, 0.f);
            #pragma unroll
            for (int i = 0; i < 8; ++i) {
                float4 pv = pc4[i];
                a4.x += w0[i].x * pv.x; a4.y += w0[i].y * pv.y;
                a4.z += w0[i].z * pv.z; a4.w += w0[i].w * pv.w;
            }
            #pragma unroll
            for (int i = 0; i < 8; ++i) {
                float4 pv = pa4[i];
                a4.x += w1[i].x * pv.x; a4.y += w1[i].y * pv.y;
                a4.z += w1[i].z * pv.z; a4.w += w1[i].w * pv.w;
            }
            const float acc = (a4.x + a4.y) + (a4.z + a4.w);
            const int gbase = (py * R + px) * CS + qoff;     // + soff -> addr
            float aggd = ab;
            #pragma unroll
            for (int k = 0; k < 4; ++k) {
                int soff = sIdx[p * 4 + k];       // wave-uniform branch
                if (soff >= 0) {
                    float val = sA[gbase + soff];
                    float aw = (k == 0) ? aw0 : (k == 1) ? aw1 : (k == 2) ? aw2 : aw3;
                    aggd += aw * val;
                }
            }
            U[p * UST + o] = aggd * acc;
            if (++px == TS) { px = 0; ++py; }
        }
    };

    __builtin_amdgcn_s_setprio(1);
    p4_body(tid, 0, NP);                       // main: one o per thread
    {
        const int wv = tid >> 6, ln = tid & 63;
        if (wv >= 1 && ln < 32) {              // tail: waves 1..3, p-thirds
            const int pbeg = (NP * (wv - 1)) / 3;
            const int pend = (NP * wv) / 3;
            if (pbeg < pend) p4_body(256 + ln, pbeg, pend);
        }
    }
    __builtin_amdgcn_s_setprio(0);
    __syncthreads();

    // ---- P5: reduce over the 9 patch positions, store ----
    for (int e = tid; e < 32 * NP; e += 256) {
        int c = e / NP, p = e - (e / NP) * NP;
        int py = p / TS, px = p - (p / TS) * TS;
        float s = 0.f;
        const float* up = U + p * UST + c * 9;
        #pragma unroll
        for (int q = 0; q < 9; ++q) s += up[q];
        out[((t * 32 + c) * H + (y0 + py)) * W + (x0 + px)] = s;
    }
}

// jax.image.resize(method='linear') 2x: half-pixel centers, edge weights renorm
// to pure clamp. even o=2m: 0.25*x[m-1]+0.75*x[m]; odd o=2m+1: 0.75*x[m]+0.25*x[m+1].
__global__ void up2_kernel(const float* __restrict__ in, float* __restrict__ out,
                           int C, int h, int w)
{
    int idx = blockIdx.x * blockDim.x + threadIdx.x;
    int H = 2 * h, W = 2 * w;
    int total = C * H * W;
    if (idx >= total) return;
    int ox = idx % W;
    int oy = (idx / W) % H;
    int c  = idx / (W * H);

    int my = oy >> 1, mx = ox >> 1;
    int y0, y1, x0, x1;
    float wy0, wy1, wx0, wx1;
    if ((oy & 1) == 0) { y0 = max(my - 1, 0); y1 = my; wy0 = 0.25f; wy1 = 0.75f; }
    else               { y0 = my; y1 = min(my + 1, h - 1); wy0 = 0.75f; wy1 = 0.25f; }
    if ((ox & 1) == 0) { x0 = max(mx - 1, 0); x1 = mx; wx0 = 0.25f; wx1 = 0.75f; }
    else               { x0 = mx; x1 = min(mx + 1, w - 1); wx0 = 0.75f; wx1 = 0.25f; }

    const float* pc = in + (size_t)c * h * w;
    float v = wy0 * (wx0 * pc[y0 * w + x0] + wx1 * pc[y0 * w + x1])
            + wy1 * (wx0 * pc[y1 * w + x0] + wx1 * pc[y1 * w + x1]);
    out[idx] = v;
}

// final: out128[o,y,x] = up_b[o] + sum_i up_w[o,i]*a1cat[i,y,x]; pixel_shuffle r=2.
// o from blockIdx.y -> weight reads scalar, a1 reads coalesced.
// Chunked reg-buffered loads (16 in flight) kill the serial L2 chain (R20 win).
__global__ __launch_bounds__(256)
void final_kernel(const float* __restrict__ a1,   // (96, 48, 48)
                  const float* __restrict__ up_w, // (128, 96)
                  const float* __restrict__ up_b, // (128)
                  float* __restrict__ out)        // (32, 96, 96)
{
    const int pix = blockIdx.x * 256 + threadIdx.x;   // 0..2303
    const int o   = blockIdx.y;                       // 0..127 (uniform)
    const int x = pix % 48, y = pix / 48;

    const float* w = up_w + o * 96;
    float a0 = up_b[o], a1p = 0.f, a2p = 0.f, a3p = 0.f;
    #pragma unroll 1
    for (int i = 0; i < 96; i += 16) {
        float v[16];
        #pragma unroll
        for (int u = 0; u < 16; ++u) v[u] = a1[(size_t)(i + u) * 2304 + pix];
        #pragma unroll
        for (int u = 0; u < 16; u += 4) {
            a0  += w[i + u]     * v[u];
            a1p += w[i + u + 1] * v[u + 1];
            a2p += w[i + u + 2] * v[u + 2];
            a3p += w[i + u + 3] * v[u + 3];
        }
    }
    float acc = (a0 + a1p) + (a2p + a3p);

    int co = o >> 2, ry = (o >> 1) & 1, rx = o & 1;
    out[((co * 96 + 2 * y + ry) * 96) + 2 * x + rx] = acc;
}

extern "C" void kernel_launch(void* const* d_in, const int* in_sizes, int n_in,
                              void* d_out, int out_size, void* d_ws, size_t ws_size,
                              hipStream_t stream)
{
    const float* feats_l1 = (const float*)d_in[0];
    const float* feats_l2 = (const float*)d_in[1];
    const float* feats_l3 = (const float*)d_in[2];
    const float* agg_l3_w = (const float*)d_in[3];
    const float* agg_l3_b = (const float*)d_in[4];
    const float* wp_l3_w  = (const float*)d_in[5];
    const float* wp_l3_b  = (const float*)d_in[6];
    const float* agg_l2_w = (const float*)d_in[7];
    const float* agg_l2_b = (const float*)d_in[8];
    const float* wp_l2_w  = (const float*)d_in[9];
    const float* wp_l2_b  = (const float*)d_in[10];
    const float* agg_l1_w = (const float*)d_in[11];
    const float* agg_l1_b = (const float*)d_in[12];
    const float* wp_l1_w  = (const float*)d_in[13];
    const float* wp_l1_b  = (const float*)d_in[14];
    const float* up_w     = (const float*)d_in[15];
    const float* up_b     = (const float*)d_in[16];
    float* out = (float*)d_out;

    float* ws   = (float*)d_ws;
    float* agg3 = ws;                  // 3*32*12*12  = 13824
    float* a3up = agg3 + 13824;        // 3*32*24*24  = 55296
    float* agg2 = a3up + 55296;        // 3*32*24*24  = 55296
    float* a2up = agg2 + 55296;        // 3*32*48*48  = 221184
    float* a1   = a2up + 221184;       // 3*32*48*48  = 221184

    // level 3 (12x12, d=3), 1x1 tiles -> 144 x 3 = 432 blocks, no add
    agg_tile<3, 1, 12, 12, false><<<dim3(144, 3), 256, 0, stream>>>(
        feats_l3, nullptr, agg_l3_w, agg_l3_b, wp_l3_w, wp_l3_b, agg3);
    up2_kernel<<<(96 * 24 * 24 + 255) / 256, 256, 0, stream>>>(agg3, a3up, 96, 12, 12);

    // level 2 (24x24, d=5), 2x2 tiles -> 144 x 3 = 432 blocks
    agg_tile<5, 2, 24, 24, true><<<dim3(144, 3), 256, 0, stream>>>(
        feats_l2, a3up, agg_l2_w, agg_l2_b, wp_l2_w, wp_l2_b, agg2);
    up2_kernel<<<(96 * 48 * 48 + 255) / 256, 256, 0, stream>>>(agg2, a2up, 96, 24, 24);

    // level 1 (48x48, d=7), 3x3 tiles -> 256 x 3 = 768 blocks (= 3/CU)
    agg_tile<7, 3, 48, 48, true><<<dim3(256, 3), 256, 0, stream>>>(
        feats_l1, a2up, agg_l1_w, agg_l1_b, wp_l1_w, wp_l1_b, a1);

    // final projection + pixel shuffle (o uniform per block -> scalar weights)
    final_kernel<<<dim3(9, 128), 256, 0, stream>>>(a1, up_w, up_b, out);
}